// Round 11
// baseline (1003.688 us; speedup 1.0000x reference)
//
#include <hip/hip_runtime.h>
#include <hip/hip_bf16.h>
#include <hip/hip_fp16.h>

static inline int cdiv(long long a, int b) { return (int)((a + b - 1) / b); }

#define LEAK 0.1f
__device__ __forceinline__ float leaky(float v) { return v >= 0.0f ? v : LEAK * v; }

// packed edge: bits[31:15] = src (17b), bits[14:0] = fp16(w) >> 1 ; 0 == null edge
__device__ __forceinline__ int dec_s(unsigned p) { return (int)(p >> 15); }
__device__ __forceinline__ float dec_w(unsigned p) {
    return __half2float(__ushort_as_half((unsigned short)((p & 0x7FFFu) << 1)));
}
__device__ __forceinline__ unsigned enc_sw(int s, float w) {
    return ((unsigned)s << 15) | ((unsigned)__half_as_ushort(__float2half_rn(w)) >> 1);
}

constexpr int BT = 256;         // threads (scan / deg kernels)
constexpr int BT2 = 512;        // threads (hist / scatter / layer kernels)
constexpr int NBLK = 1024;      // edge-partition blocks (phases A/C)
constexpr int CHUNK = 4096;     // edges staged in LDS per pass (phase C)
constexpr int BINB = 128;       // nodes per bin
constexpr int BINS_MAX = 1024;  // >= cdiv(N,BINB) = 782 for N=100k

// ---------------- phase A: per-(bin, block) histogram of dst>>7 (also zeroes g) ----------------
__global__ __launch_bounds__(BT2) void k_hist(const int* __restrict__ dst, int* __restrict__ hist,
                                              float* __restrict__ g, int E, int EPB, int nbins) {
    __shared__ int h[BINS_MAX];
    if (blockIdx.x == 0 && threadIdx.x < 48) g[threadIdx.x] = 0.0f;  // pool accumulator init
    for (int i = threadIdx.x; i < nbins; i += BT2) h[i] = 0;
    __syncthreads();
    int base = blockIdx.x * EPB;
    int end = min(base + EPB, E);
    for (int i = base + threadIdx.x; i < end; i += BT2) atomicAdd(&h[dst[i] >> 7], 1);
    __syncthreads();
    for (int i = threadIdx.x; i < nbins; i += BT2) hist[(size_t)i * NBLK + blockIdx.x] = h[i];
}

// ---------------- phase B1: exclusive scan of each bin's row over blocks ----------------
__global__ __launch_bounds__(BT) void k_scan_cols(int* __restrict__ hist, int* __restrict__ binTot) {
    __shared__ int a[NBLK], b_[NBLK];
    int t = threadIdx.x;
    int* H = hist + (size_t)blockIdx.x * NBLK;
    for (int i = t; i < NBLK; i += BT) a[i] = H[i];
    __syncthreads();
    int* cur = a; int* nxt = b_;
    for (int off = 1; off < NBLK; off <<= 1) {
        for (int i = t; i < NBLK; i += BT) nxt[i] = cur[i] + (i >= off ? cur[i - off] : 0);
        __syncthreads();
        int* tm = cur; cur = nxt; nxt = tm;
    }
    for (int i = t; i < NBLK; i += BT) H[i] = (i ? cur[i - 1] : 0);
    if (t == 0) binTot[blockIdx.x] = cur[NBLK - 1];
}

// ---------------- phase B2: exclusive scan over bins ----------------
__global__ __launch_bounds__(BT) void k_scan_bins(const int* __restrict__ binTot,
                                                  int* __restrict__ binBase, int nbins) {
    __shared__ int a[BINS_MAX], b_[BINS_MAX];
    int t = threadIdx.x;
    for (int i = t; i < BINS_MAX; i += BT) a[i] = (i < nbins) ? binTot[i] : 0;
    __syncthreads();
    int* cur = a; int* nxt = b_;
    for (int off = 1; off < BINS_MAX; off <<= 1) {
        for (int i = t; i < BINS_MAX; i += BT) nxt[i] = cur[i] + (i >= off ? cur[i - off] : 0);
        __syncthreads();
        int* tm = cur; cur = nxt; nxt = tm;
    }
    for (int i = t; i < nbins; i += BT) binBase[i] = (i ? cur[i - 1] : 0);
    if (t == 0) binBase[nbins] = cur[nbins - 1];  // == E
}

// ---------------- phase C: LDS-staged scatter of edges into bin order ----------------
__global__ __launch_bounds__(BT2) void k_scatter_bins(
    const int* __restrict__ src, const int* __restrict__ dst, const float* __restrict__ ew,
    const int* __restrict__ colOff, const int* __restrict__ binBase,
    unsigned* __restrict__ sortedP, unsigned char* __restrict__ sortedDlo,
    int E, int EPB, int nbins) {
    constexpr int EPT = CHUNK / BT2;  // 8 edges per thread per chunk
    __shared__ unsigned sP[CHUNK];        // 16 KB
    __shared__ unsigned char sD[CHUNK];   // 4 KB
    __shared__ unsigned short sB[CHUNK];  // 8 KB
    __shared__ int h[BINS_MAX], sc[BINS_MAX], sc2[BINS_MAX];
    __shared__ int blkOff[BINS_MAX], cursor[BINS_MAX];

    int t = threadIdx.x, blk = blockIdx.x;
    for (int i = t; i < nbins; i += BT2) {
        blkOff[i] = binBase[i] + colOff[(size_t)i * NBLK + blk];
        cursor[i] = 0;
    }
    int base = blk * EPB;
    int bend = min(base + EPB, E);
    for (int cb = base; cb < bend; cb += CHUNK) {
        int cnt = min(CHUNK, bend - cb);
        for (int i = t; i < BINS_MAX; i += BT2) h[i] = 0;
        __syncthreads();
        int myBin[EPT], myRank[EPT], myD[EPT];
        unsigned myP[EPT];
#pragma unroll
        for (int k = 0; k < EPT; k++) {
            int li = k * BT2 + t;
            if (li < cnt) {
                int i = cb + li;
                int d = dst[i];
                myP[k] = enc_sw(src[i], ew[i]);
                myD[k] = d & (BINB - 1);
                int b = d >> 7;
                myBin[k] = b;
                myRank[k] = atomicAdd(&h[b], 1);
            } else myBin[k] = -1;
        }
        __syncthreads();
        for (int i = t; i < BINS_MAX; i += BT2) sc[i] = (i < nbins) ? h[i] : 0;
        __syncthreads();
        int* cur = sc; int* nxt = sc2;
        for (int off = 1; off < BINS_MAX; off <<= 1) {
            for (int i = t; i < BINS_MAX; i += BT2) nxt[i] = cur[i] + (i >= off ? cur[i - off] : 0);
            __syncthreads();
            int* tm = cur; cur = nxt; nxt = tm;
        }
#pragma unroll
        for (int k = 0; k < EPT; k++) {
            int b = myBin[k];
            if (b >= 0) {
                int pos = (b ? cur[b - 1] : 0) + myRank[k];
                sP[pos] = myP[k];
                sD[pos] = (unsigned char)myD[k];
                sB[pos] = (unsigned short)b;
            }
        }
        __syncthreads();
        for (int i = t; i < cnt; i += BT2) {
            int b = sB[i];
            int excl = (b ? cur[b - 1] : 0);
            int go = blkOff[b] + cursor[b] + (i - excl);
            sortedP[go] = sP[i];
            sortedDlo[go] = sD[i];
        }
        __syncthreads();
        for (int i = t; i < nbins; i += BT2) cursor[i] += h[i];
        __syncthreads();
    }
}

// ---------------- k_deg: per-bin weighted degree -> dinv, x~0 = dinv*xin (fp16) ----------------
__global__ __launch_bounds__(BT) void k_deg(
    const unsigned* __restrict__ sortedP, const unsigned char* __restrict__ sortedDlo,
    const int* __restrict__ binBase, const float* __restrict__ xin,
    float* __restrict__ dinv, __half2* __restrict__ x0h, int N) {
    __shared__ float deg[BINB];
    int t = threadIdx.x, bin = blockIdx.x;
    if (t < BINB) deg[t] = 0.0f;
    __syncthreads();
    int e0 = binBase[bin], e1 = binBase[bin + 1];
    for (int e = e0 + t; e < e1; e += BT) atomicAdd(&deg[sortedDlo[e]], dec_w(sortedP[e]));
    __syncthreads();
    if (t < BINB) {
        int node = (bin << 7) + t;
        if (node < N) {
            float d = 1.0f + deg[t];
            float di = rsqrtf(d);
            dinv[node] = di;
            float4 xv = *reinterpret_cast<const float4*>(xin + (size_t)node * 4);
            x0h[(size_t)node * 2 + 0] = __floats2half2_rn(xv.x * di, xv.y * di);
            x0h[(size_t)node * 2 + 1] = __floats2half2_rn(xv.z * di, xv.w * di);
        }
    }
}

// ---------------- edge-parallel fused layer: LDS agg + lane-split matmul ----------------
// One block per bin (128 nodes). Phase 1: stream bin edges coalesced, accumulate
// w * x~[src] into agg[128][FIN] (LDS f32 atomics, zero divergence). Phase 2: +self,
// then 4-lane-per-node matmul; out x~' = dinv*leaky(dv*agg@W+b) as fp16, split at SPLIT.
template <int FIN, int FOUT, int SPLIT>
__global__ __launch_bounds__(BT2) void k_elayer(
    const unsigned* __restrict__ sortedP, const unsigned char* __restrict__ sortedDlo,
    const int* __restrict__ binBase, const __half2* __restrict__ x,
    const float* __restrict__ dinv, const float* __restrict__ W, const float* __restrict__ b,
    __half* __restrict__ outA, __half* __restrict__ outB, int N) {
    constexpr int H = FIN / 2;
    constexpr int AGP = FIN + 1;   // padded agg stride -> conflict-free matmul reads
    constexpr int P = FOUT + 1;
    constexpr int CPL = FOUT / 4;
    __shared__ float agg[BINB * AGP];
    __shared__ float Ws[FIN * P];
    __shared__ float bs[FOUT];
    int t = threadIdx.x, bin = blockIdx.x;
    for (int i = t; i < FIN * FOUT; i += BT2) Ws[(i / FOUT) * P + (i % FOUT)] = W[i];
    for (int i = t; i < FOUT; i += BT2) bs[i] = b[i];
    for (int i = t; i < BINB * AGP; i += BT2) agg[i] = 0.0f;
    __syncthreads();
    int e0 = binBase[bin], e1 = binBase[bin + 1];
    for (int e = e0 + t; e < e1; e += 2 * BT2) {   // 2 edges in flight per thread
        int e2 = e + BT2;
        bool has2 = e2 < e1;
        unsigned p1 = sortedP[e];
        unsigned p2 = has2 ? sortedP[e2] : 0u;
        int d1 = sortedDlo[e];
        int d2 = has2 ? sortedDlo[e2] : 0;
        const __half2* r1 = x + (size_t)dec_s(p1) * H;
        const __half2* r2 = x + (size_t)dec_s(p2) * H;
        float w1 = dec_w(p1);
        float w2 = has2 ? dec_w(p2) : 0.0f;
        __half2 v1[H], v2[H];
#pragma unroll
        for (int m = 0; m < H; m++) v1[m] = r1[m];
#pragma unroll
        for (int m = 0; m < H; m++) v2[m] = r2[m];
        float* a1 = agg + d1 * AGP;
        float* a2 = agg + d2 * AGP;
#pragma unroll
        for (int m = 0; m < H; m++) {
            float2 f = __half22float2(v1[m]);
            atomicAdd(a1 + 2 * m, f.x * w1);
            atomicAdd(a1 + 2 * m + 1, f.y * w1);
        }
#pragma unroll
        for (int m = 0; m < H; m++) {
            float2 f = __half22float2(v2[m]);
            atomicAdd(a2 + 2 * m, f.x * w2);
            atomicAdd(a2 + 2 * m + 1, f.y * w2);
        }
    }
    __syncthreads();
    int nodeBase = bin << 7;
    // self-loop (unique (node, feature) per index -> no atomics)
    for (int i = t; i < BINB * H; i += BT2) {
        int d = i / H, m = i - d * H;
        int node = nodeBase + d;
        if (node < N) {
            float2 f = __half22float2(x[(size_t)node * H + m]);
            agg[d * AGP + 2 * m] += f.x;
            agg[d * AGP + 2 * m + 1] += f.y;
        }
    }
    __syncthreads();
    int d = t >> 2, l = t & 3;
    int node = nodeBase + d;
    if (node >= N) return;
    float dv = dinv[node];
    float p[CPL];
#pragma unroll
    for (int q = 0; q < CPL; q++) p[q] = 0.0f;
    for (int f = 0; f < FIN; f++) {
        float a = agg[d * AGP + f];
        const float* wr = Ws + f * P;
#pragma unroll
        for (int q = 0; q < CPL; q++) p[q] += a * wr[l + 4 * q];
    }
#pragma unroll
    for (int q = 0; q < CPL; q++) {
        int j = l + 4 * q;
        float aout = leaky(dv * p[q] + bs[j]) * dv;
        __half hv = __float2half_rn(aout);
        if (j < SPLIT) outA[(size_t)node * SPLIT + j] = hv;
        else outB[(size_t)node * (FOUT - SPLIT) + (j - SPLIT)] = hv;
    }
}

// ---------------- layer-3 pass A: edge-parallel agg of h2a -> ya [N][12] fp32 ----------------
__global__ __launch_bounds__(BT2) void k_e3a(
    const unsigned* __restrict__ sortedP, const unsigned char* __restrict__ sortedDlo,
    const int* __restrict__ binBase, const __half2* __restrict__ xa,
    float* __restrict__ ya, int N) {
    constexpr int H = 6, FIN = 12, AGP = FIN + 1;
    __shared__ float agg[BINB * AGP];
    int t = threadIdx.x, bin = blockIdx.x;
    for (int i = t; i < BINB * AGP; i += BT2) agg[i] = 0.0f;
    __syncthreads();
    int e0 = binBase[bin], e1 = binBase[bin + 1];
    for (int e = e0 + t; e < e1; e += 2 * BT2) {
        int e2 = e + BT2;
        bool has2 = e2 < e1;
        unsigned p1 = sortedP[e];
        unsigned p2 = has2 ? sortedP[e2] : 0u;
        int d1 = sortedDlo[e];
        int d2 = has2 ? sortedDlo[e2] : 0;
        const __half2* r1 = xa + (size_t)dec_s(p1) * H;
        const __half2* r2 = xa + (size_t)dec_s(p2) * H;
        float w1 = dec_w(p1);
        float w2 = has2 ? dec_w(p2) : 0.0f;
        __half2 v1[H], v2[H];
#pragma unroll
        for (int m = 0; m < H; m++) v1[m] = r1[m];
#pragma unroll
        for (int m = 0; m < H; m++) v2[m] = r2[m];
        float* a1 = agg + d1 * AGP;
        float* a2 = agg + d2 * AGP;
#pragma unroll
        for (int m = 0; m < H; m++) {
            float2 f = __half22float2(v1[m]);
            atomicAdd(a1 + 2 * m, f.x * w1);
            atomicAdd(a1 + 2 * m + 1, f.y * w1);
        }
#pragma unroll
        for (int m = 0; m < H; m++) {
            float2 f = __half22float2(v2[m]);
            atomicAdd(a2 + 2 * m, f.x * w2);
            atomicAdd(a2 + 2 * m + 1, f.y * w2);
        }
    }
    __syncthreads();
    int nodeBase = bin << 7;
    for (int i = t; i < BINB * H; i += BT2) {  // self-loop
        int d = i / H, m = i - d * H;
        int node = nodeBase + d;
        if (node < N) {
            float2 f = __half22float2(xa[(size_t)node * H + m]);
            agg[d * AGP + 2 * m] += f.x;
            agg[d * AGP + 2 * m + 1] += f.y;
        }
    }
    __syncthreads();
    for (int i = t; i < BINB * FIN; i += BT2) {  // coalesced fp32 write
        int d = i / FIN, f = i - d * FIN;
        int node = nodeBase + d;
        if (node < N) ya[(size_t)node * FIN + f] = agg[d * AGP + f];
    }
}

// ---------------- layer-3 pass B: edge-parallel agg of h2b + ya -> 24x48 matmul+pool ----------------
__global__ __launch_bounds__(BT2) void k_e3b(
    const unsigned* __restrict__ sortedP, const unsigned char* __restrict__ sortedDlo,
    const int* __restrict__ binBase, const __half2* __restrict__ xb,
    const float* __restrict__ ya, const float* __restrict__ dinv,
    const float* __restrict__ W, const float* __restrict__ b,
    float* __restrict__ g, int N) {
    constexpr int H = 6, FINH = 12, AGP = FINH + 1, FOUT = 48, P = FOUT + 1, CPL = 12;
    __shared__ float agg[BINB * AGP];
    __shared__ float Ws[24 * P];
    __shared__ float bs[FOUT];
    __shared__ float pool[FOUT];
    int t = threadIdx.x, bin = blockIdx.x;
    for (int i = t; i < 24 * FOUT; i += BT2) Ws[(i / FOUT) * P + (i % FOUT)] = W[i];
    for (int i = t; i < FOUT; i += BT2) { bs[i] = b[i]; pool[i] = 0.0f; }
    for (int i = t; i < BINB * AGP; i += BT2) agg[i] = 0.0f;
    __syncthreads();
    int e0 = binBase[bin], e1 = binBase[bin + 1];
    for (int e = e0 + t; e < e1; e += 2 * BT2) {
        int e2 = e + BT2;
        bool has2 = e2 < e1;
        unsigned p1 = sortedP[e];
        unsigned p2 = has2 ? sortedP[e2] : 0u;
        int d1 = sortedDlo[e];
        int d2 = has2 ? sortedDlo[e2] : 0;
        const __half2* r1 = xb + (size_t)dec_s(p1) * H;
        const __half2* r2 = xb + (size_t)dec_s(p2) * H;
        float w1 = dec_w(p1);
        float w2 = has2 ? dec_w(p2) : 0.0f;
        __half2 v1[H], v2[H];
#pragma unroll
        for (int m = 0; m < H; m++) v1[m] = r1[m];
#pragma unroll
        for (int m = 0; m < H; m++) v2[m] = r2[m];
        float* a1 = agg + d1 * AGP;
        float* a2 = agg + d2 * AGP;
#pragma unroll
        for (int m = 0; m < H; m++) {
            float2 f = __half22float2(v1[m]);
            atomicAdd(a1 + 2 * m, f.x * w1);
            atomicAdd(a1 + 2 * m + 1, f.y * w1);
        }
#pragma unroll
        for (int m = 0; m < H; m++) {
            float2 f = __half22float2(v2[m]);
            atomicAdd(a2 + 2 * m, f.x * w2);
            atomicAdd(a2 + 2 * m + 1, f.y * w2);
        }
    }
    __syncthreads();
    int nodeBase = bin << 7;
    for (int i = t; i < BINB * H; i += BT2) {  // self-loop for the b-half
        int d = i / H, m = i - d * H;
        int node = nodeBase + d;
        if (node < N) {
            float2 f = __half22float2(xb[(size_t)node * H + m]);
            agg[d * AGP + 2 * m] += f.x;
            agg[d * AGP + 2 * m + 1] += f.y;
        }
    }
    __syncthreads();
    int d = t >> 2, l = t & 3;
    int node = nodeBase + d;
    if (node < N) {
        float dv = dinv[node];
        float p[CPL];
#pragma unroll
        for (int q = 0; q < CPL; q++) p[q] = 0.0f;
        const float* yr = ya + (size_t)node * 12;
        for (int f = 0; f < 12; f++) {           // a-half: features 0-11 (ya)
            float a = yr[f];
            const float* wr = Ws + f * P;
#pragma unroll
            for (int q = 0; q < CPL; q++) p[q] += a * wr[l + 4 * q];
        }
        for (int f = 0; f < 12; f++) {           // b-half: features 12-23 (LDS agg)
            float a = agg[d * AGP + f];
            const float* wr = Ws + (12 + f) * P;
#pragma unroll
            for (int q = 0; q < CPL; q++) p[q] += a * wr[l + 4 * q];
        }
#pragma unroll
        for (int q = 0; q < CPL; q++) {
            int j = l + 4 * q;
            atomicAdd(&pool[j], leaky(dv * p[q] + bs[j]));
        }
    }
    __syncthreads();
    if (t < FOUT) atomicAdd(&g[t], pool[t]);
}

// ---------------- FC head: g[48] -> 32 -> 16 -> 2 ----------------
__global__ void k_head(const float* __restrict__ g,
                       const float* __restrict__ fcW1, const float* __restrict__ fcb1,
                       const float* __restrict__ fcW2, const float* __restrict__ fcb2,
                       const float* __restrict__ fcW3, const float* __restrict__ fcb3,
                       float* __restrict__ out) {
    __shared__ float gs[48], t1[32], t2[16];
    int t = threadIdx.x;
    if (t < 48) gs[t] = g[t];
    __syncthreads();
    if (t < 32) {
        float a = fcb1[t];
#pragma unroll
        for (int k = 0; k < 48; k++) a += gs[k] * fcW1[k * 32 + t];
        t1[t] = leaky(a);
    }
    __syncthreads();
    if (t < 16) {
        float a = fcb2[t];
#pragma unroll
        for (int k = 0; k < 32; k++) a += t1[k] * fcW2[k * 16 + t];
        t2[t] = leaky(a);
    }
    __syncthreads();
    if (t < 2) {
        float a = fcb3[t];
#pragma unroll
        for (int k = 0; k < 16; k++) a += t2[k] * fcW3[k * 2 + t];
        out[t] = a;
    }
}

extern "C" void kernel_launch(void* const* d_in, const int* in_sizes, int n_in,
                              void* d_out, int out_size, void* d_ws, size_t ws_size,
                              hipStream_t stream) {
    const float* xin = (const float*)d_in[0];   // [N,4]
    const float* ew  = (const float*)d_in[1];   // [E]
    const int*   ei  = (const int*)d_in[2];     // [2,E]
    const float* W1  = (const float*)d_in[3];
    const float* b1  = (const float*)d_in[4];
    const float* W2  = (const float*)d_in[5];
    const float* b2  = (const float*)d_in[6];
    const float* W3  = (const float*)d_in[7];
    const float* b3  = (const float*)d_in[8];
    const float* fcW1 = (const float*)d_in[9];
    const float* fcb1 = (const float*)d_in[10];
    const float* fcW2 = (const float*)d_in[11];
    const float* fcb2 = (const float*)d_in[12];
    const float* fcW3 = (const float*)d_in[13];
    const float* fcb3 = (const float*)d_in[14];

    const int N = in_sizes[0] / 4;
    const int E = in_sizes[1];
    const int* src = ei;
    const int* dst = ei + E;
    const int nbins = cdiv(N, BINB);       // 782 for N=100k
    const int EPB = cdiv(E, NBLK);         // 3125 -> single chunk per scatter block

    // workspace layout, 16B-aligned chunks
    char* p_ = (char*)d_ws;
    auto alloc = [&](size_t bytes) { char* r = p_; p_ += (bytes + 15) & ~(size_t)15; return r; };
    unsigned* sortedP = (unsigned*)alloc((size_t)E * 4);
    unsigned char* sortedDlo = (unsigned char*)alloc((size_t)E);
    int*   hist    = (int*)alloc((size_t)BINS_MAX * NBLK * 4);
    int*   binTot  = (int*)alloc((size_t)BINS_MAX * 4);
    int*   binBase = (int*)alloc((size_t)(BINS_MAX + 1) * 4);
    float* dinv    = (float*)alloc((size_t)N * 4);
    __half2* x0h   = (__half2*)alloc((size_t)N * 2 * 4);   // [N][2]  x~0
    __half*  h1    = (__half*)alloc((size_t)N * 12 * 2);   // [N][12] x~1
    __half*  h2a   = (__half*)alloc((size_t)N * 12 * 2);   // [N][12] x~2 feats 0-11
    __half*  h2b   = (__half*)alloc((size_t)N * 12 * 2);   // [N][12] x~2 feats 12-23
    float* ya      = (float*)alloc((size_t)N * 12 * 4);    // [N][12] l3 agg feats 0-11
    float* g       = (float*)alloc(48 * 4);

    // --- sort-to-bin build (no fabric atomics, no CSR); k_hist also zeroes g ---
    k_hist<<<NBLK, BT2, 0, stream>>>(dst, hist, g, E, EPB, nbins);
    k_scan_cols<<<nbins, BT, 0, stream>>>(hist, binTot);
    k_scan_bins<<<1, BT, 0, stream>>>(binTot, binBase, nbins);
    k_scatter_bins<<<NBLK, BT2, 0, stream>>>(src, dst, ew, hist, binBase,
                                             sortedP, sortedDlo, E, EPB, nbins);
    k_deg<<<nbins, BT, 0, stream>>>(sortedP, sortedDlo, binBase, xin, dinv, x0h, N);

    // --- 3 GCN layers, edge-parallel LDS aggregation (no divergence) ---
    k_elayer<4, 12, 12><<<nbins, BT2, 0, stream>>>(
        sortedP, sortedDlo, binBase, x0h, dinv, W1, b1, h1, h1, N);
    k_elayer<12, 24, 12><<<nbins, BT2, 0, stream>>>(
        sortedP, sortedDlo, binBase, (const __half2*)h1, dinv, W2, b2, h2a, h2b, N);
    k_e3a<<<nbins, BT2, 0, stream>>>(
        sortedP, sortedDlo, binBase, (const __half2*)h2a, ya, N);
    k_e3b<<<nbins, BT2, 0, stream>>>(
        sortedP, sortedDlo, binBase, (const __half2*)h2b, ya, dinv, W3, b3, g, N);

    // --- FC head ---
    k_head<<<1, 64, 0, stream>>>(g, fcW1, fcb1, fcW2, fcb2, fcW3, fcb3, (float*)d_out);
}

// Round 12
// 267.900 us; speedup vs baseline: 3.7465x; 3.7465x over previous
//
#include <hip/hip_runtime.h>
#include <hip/hip_bf16.h>
#include <hip/hip_fp16.h>

static inline int cdiv(long long a, int b) { return (int)((a + b - 1) / b); }

#define LEAK 0.1f
__device__ __forceinline__ float leaky(float v) { return v >= 0.0f ? v : LEAK * v; }

// packed edge: bits[31:15] = src (17b), bits[14:0] = fp16(w) >> 1 ; 0 == zero-pad edge
__device__ __forceinline__ int dec_s(unsigned p) { return (int)(p >> 15); }
__device__ __forceinline__ float dec_w(unsigned p) {
    return __half2float(__ushort_as_half((unsigned short)((p & 0x7FFFu) << 1)));
}
__device__ __forceinline__ unsigned enc_sw(int s, float w) {
    return ((unsigned)s << 15) | ((unsigned)__half_as_ushort(__float2half_rn(w)) >> 1);
}

constexpr int BT = 256;        // threads per block (scan kernels)
constexpr int BT2 = 512;       // threads per block (hist / scatter / bin_sort)
constexpr int NBLK = 512;      // edge-partition blocks (phases A/C)
constexpr int CHUNK = 4096;    // edges staged in LDS per pass (phase C)
constexpr int BINS_MAX = 512;  // >= (N+255)/256 for N=100k (391)
constexpr int BIN_PAD = 1024;  // per-bin slack in pairs[] for row padding
constexpr int MAXE = 11264;    // LDS staging capacity per bin (mean 8192, +34 sigma)

// ---------------- phase A: per-(bin, block) histogram of dst>>8 (also zeroes g) ----------------
__global__ __launch_bounds__(BT2) void k_hist(const int* __restrict__ dst, int* __restrict__ hist,
                                              float* __restrict__ g, int E, int EPB, int nbins) {
    __shared__ int h[BINS_MAX];
    if (blockIdx.x == 0 && threadIdx.x < 48) g[threadIdx.x] = 0.0f;  // pool accumulator init
    for (int i = threadIdx.x; i < nbins; i += BT2) h[i] = 0;
    __syncthreads();
    int base = blockIdx.x * EPB;
    int end = min(base + EPB, E);
    for (int i = base + threadIdx.x; i < end; i += BT2) atomicAdd(&h[dst[i] >> 8], 1);
    __syncthreads();
    for (int i = threadIdx.x; i < nbins; i += BT2) hist[(size_t)i * NBLK + blockIdx.x] = h[i];
}

// ---------------- phase B1: exclusive scan of each bin's row over blocks ----------------
__global__ __launch_bounds__(BT) void k_scan_cols(int* __restrict__ hist, int* __restrict__ binTot) {
    __shared__ int a[NBLK], b_[NBLK];
    int t = threadIdx.x;
    int* H = hist + (size_t)blockIdx.x * NBLK;
    for (int i = t; i < NBLK; i += BT) a[i] = H[i];
    __syncthreads();
    int* cur = a; int* nxt = b_;
    for (int off = 1; off < NBLK; off <<= 1) {
        for (int i = t; i < NBLK; i += BT) nxt[i] = cur[i] + (i >= off ? cur[i - off] : 0);
        __syncthreads();
        int* tm = cur; cur = nxt; nxt = tm;
    }
    for (int i = t; i < NBLK; i += BT) H[i] = (i ? cur[i - 1] : 0);
    if (t == 0) binTot[blockIdx.x] = cur[NBLK - 1];
}

// ---------------- phase B2: exclusive scan over bins ----------------
__global__ __launch_bounds__(BT) void k_scan_bins(const int* __restrict__ binTot,
                                                  int* __restrict__ binBase, int nbins) {
    __shared__ int a[BINS_MAX], b_[BINS_MAX];
    int t = threadIdx.x;
    for (int i = t; i < BINS_MAX; i += BT) a[i] = (i < nbins) ? binTot[i] : 0;
    __syncthreads();
    int* cur = a; int* nxt = b_;
    for (int off = 1; off < BINS_MAX; off <<= 1) {
        for (int i = t; i < BINS_MAX; i += BT) nxt[i] = cur[i] + (i >= off ? cur[i - off] : 0);
        __syncthreads();
        int* tm = cur; cur = nxt; nxt = tm;
    }
    for (int i = t; i < nbins; i += BT) binBase[i] = (i ? cur[i - 1] : 0);
    if (t == 0) binBase[nbins] = cur[nbins - 1];  // == E
}

// ---------------- phase C: LDS-staged scatter of edges into bin order ----------------
__global__ __launch_bounds__(BT2) void k_scatter_bins(
    const int* __restrict__ src, const int* __restrict__ dst, const float* __restrict__ ew,
    const int* __restrict__ colOff, const int* __restrict__ binBase,
    unsigned* __restrict__ sortedP, unsigned char* __restrict__ sortedDlo,
    int E, int EPB, int nbins) {
    constexpr int EPT = CHUNK / BT2;  // 8 edges per thread per chunk
    __shared__ unsigned sP[CHUNK];        // 16 KB
    __shared__ unsigned char sD[CHUNK];   // 4 KB
    __shared__ unsigned short sB[CHUNK];  // 8 KB
    __shared__ int h[BINS_MAX], sc[BINS_MAX], sc2[BINS_MAX];
    __shared__ int blkOff[BINS_MAX], cursor[BINS_MAX];

    int t = threadIdx.x, blk = blockIdx.x;
    if (t < nbins) {
        blkOff[t] = binBase[t] + colOff[(size_t)t * NBLK + blk];
        cursor[t] = 0;
    }
    int base = blk * EPB;
    int bend = min(base + EPB, E);
    for (int cb = base; cb < bend; cb += CHUNK) {
        int cnt = min(CHUNK, bend - cb);
        if (t < BINS_MAX) h[t] = 0;
        __syncthreads();
        int myBin[EPT], myRank[EPT], myD[EPT];
        unsigned myP[EPT];
#pragma unroll
        for (int k = 0; k < EPT; k++) {
            int li = k * BT2 + t;
            if (li < cnt) {
                int i = cb + li;
                int d = dst[i];
                myP[k] = enc_sw(src[i], ew[i]);
                myD[k] = d & 255;
                int b = d >> 8;
                myBin[k] = b;
                myRank[k] = atomicAdd(&h[b], 1);
            } else myBin[k] = -1;
        }
        __syncthreads();
        if (t < BINS_MAX) sc[t] = (t < nbins) ? h[t] : 0;
        __syncthreads();
        int* cur = sc; int* nxt = sc2;
        for (int off = 1; off < BINS_MAX; off <<= 1) {
            if (t < BINS_MAX) nxt[t] = cur[t] + (t >= off ? cur[t - off] : 0);
            __syncthreads();
            int* tm = cur; cur = nxt; nxt = tm;
        }
#pragma unroll
        for (int k = 0; k < EPT; k++) {
            int b = myBin[k];
            if (b >= 0) {
                int pos = (b ? cur[b - 1] : 0) + myRank[k];
                sP[pos] = myP[k];
                sD[pos] = (unsigned char)myD[k];
                sB[pos] = (unsigned short)b;
            }
        }
        __syncthreads();
        for (int i = t; i < cnt; i += BT2) {
            int b = sB[i];
            int excl = (b ? cur[b - 1] : 0);
            int go = blkOff[b] + cursor[b] + (i - excl);
            sortedP[go] = sP[i];
            sortedDlo[go] = sD[i];
        }
        __syncthreads();
        if (t < nbins) cursor[t] += h[t];
        __syncthreads();
    }
}

// ---------------- phase D: per-bin counting sort -> padded CSR (degree-sorted slots) ----------------
// Emits slot-indexed rowbegS/rowcntS/nodeIdS with the bin's 256 nodes ordered by padded
// degree (bitonic), so gather waves serve near-equal-degree nodes. pairs written via
// LDS staging + coalesced uint4 stream-out. Also computes dinv, x~0 = dinv*xin (fp16).
__global__ __launch_bounds__(BT2) void k_bin_sort(
    const unsigned* __restrict__ sortedP, const unsigned char* __restrict__ sortedDlo,
    const int* __restrict__ binBase, const float* __restrict__ xin,
    unsigned* __restrict__ pairs, int* __restrict__ rowbegS, int* __restrict__ rowcntS,
    int* __restrict__ nodeIdS, float* __restrict__ dinv, __half2* __restrict__ x0h, int N) {
    __shared__ unsigned sPairs[MAXE];                     // 44 KB
    __shared__ int cntA[256], exA[256], sA[256], sB_[256], cursor[256], keyA[256];
    __shared__ float degs[256];
    int bin = blockIdx.x, t = threadIdx.x;
    int e0 = binBase[bin], e1 = binBase[bin + 1];
    int e0p = ((e0 + 3) & ~3) + bin * BIN_PAD;  // aligned padded base for this bin
    int nodeBase = bin << 8;
    int nn = min(256, N - nodeBase);
    if (t < 256) { cntA[t] = 0; degs[t] = 0.0f; }
    __syncthreads();
    for (int i = e0 + t; i < e1; i += BT2) {
        atomicAdd(&cntA[sortedDlo[i]], 1);
        atomicAdd(&degs[sortedDlo[i]], dec_w(sortedP[i]));
    }
    __syncthreads();
    int pc = 0;
    if (t < 256) {
        pc = (cntA[t] + 3) & ~3;  // padded count (multiple of 4)
        sA[t] = pc;
    }
    __syncthreads();
    int* cur = sA; int* nxt = sB_;
    for (int off = 1; off < 256; off <<= 1) {
        if (t < 256) nxt[t] = cur[t] + (t >= off ? cur[t - off] : 0);
        __syncthreads();
        int* tm = cur; cur = nxt; nxt = tm;
    }
    int padTot = 0;
    if (t < 256) {
        exA[t] = (t ? cur[t - 1] : 0);  // exclusive padded offset
        cursor[t] = 0;
        keyA[t] = (pc << 8) | t;        // sort key: padded degree, tie-break node
    }
    padTot = cur[255];  // uniform after sync below
    __syncthreads();
    // place edges into LDS in node order
    for (int i = e0 + t; i < e1; i += BT2) {
        int dl = sortedDlo[i];
        int r = atomicAdd(&cursor[dl], 1);
        int pos = exA[dl] + r;
        if (pos < MAXE) sPairs[pos] = sortedP[i];
    }
    // bitonic sort keyA ascending (groups equal-degree nodes into adjacent slots)
    for (int k = 2; k <= 256; k <<= 1) {
        for (int j = k >> 1; j > 0; j >>= 1) {
            __syncthreads();
            if (t < 256) {
                int ixj = t ^ j;
                if (ixj > t) {
                    int ka = keyA[t], kb = keyA[ixj];
                    bool up = ((t & k) == 0);
                    if (up ? (ka > kb) : (ka < kb)) {
                        keyA[t] = kb;
                        keyA[ixj] = ka;
                    }
                }
            }
        }
    }
    __syncthreads();
    if (t < 256) {
        // zero-fill pad slots of my node
        int realc = cntA[t], mypc = (realc + 3) & ~3, ex = exA[t];
        for (int z = realc; z < mypc; z++)
            if (ex + z < MAXE) sPairs[ex + z] = 0u;
        // slot outputs (degree-sorted order)
        int o = keyA[t] & 255;
        int slot = nodeBase + t;  // slot index space == node index space size
        rowbegS[slot] = e0p + exA[o];
        rowcntS[slot] = (cntA[o] + 3) & ~3;
        nodeIdS[slot] = nodeBase + o;
        // node stats (by original node id)
        if (t < nn) {
            int node = nodeBase + t;
            float d = 1.0f + degs[t];
            float di = rsqrtf(d);
            dinv[node] = di;
            float4 xv = *reinterpret_cast<const float4*>(xin + (size_t)node * 4);
            x0h[(size_t)node * 2 + 0] = __floats2half2_rn(xv.x * di, xv.y * di);
            x0h[(size_t)node * 2 + 1] = __floats2half2_rn(xv.z * di, xv.w * di);
        }
    }
    __syncthreads();
    // coalesced stream-out of the staged, padded, node-ordered edge block
    int nv = min(padTot, MAXE) >> 2;
    uint4* dstv = reinterpret_cast<uint4*>(pairs + e0p);
    const uint4* srcv = reinterpret_cast<const uint4*>(sPairs);
    for (int i = t; i < nv; i += BT2) dstv[i] = srcv[i];
}

// ---------------- fused layer (layers 1,2): slot-indexed, lane-split output columns ----------------
template <int FIN, int FOUT, int TPN, int SPLIT>
__global__ void k_layer(const int* __restrict__ rowbegS, const int* __restrict__ rowcntS,
                        const int* __restrict__ nodeIdS, const unsigned* __restrict__ pairs,
                        const __half2* __restrict__ x, const float* __restrict__ dinv,
                        const float* __restrict__ W, const float* __restrict__ b,
                        __half* __restrict__ outA, __half* __restrict__ outB, int nSlots, int N) {
    constexpr int H = FIN / 2;
    constexpr int P = FOUT + 1;
    constexpr int KX = (H + TPN - 1) / TPN;
    constexpr int CPL = FOUT / TPN;  // columns per lane
    __shared__ float Ws[FIN * P];
    __shared__ float bs[FOUT];
    for (int t = threadIdx.x; t < FIN * FOUT; t += blockDim.x) {
        int r = t / FOUT, c = t - r * FOUT;
        Ws[r * P + c] = W[t];
    }
    for (int t = threadIdx.x; t < FOUT; t += blockDim.x) bs[t] = b[t];
    __syncthreads();
    int gid = blockIdx.x * blockDim.x + threadIdx.x;
    int s = gid / TPN;
    int l = gid & (TPN - 1);
    if (s >= nSlots) return;
    int node = nodeIdS[s];
    if (node >= N) return;
    int beg = rowbegS[s], pc = rowcntS[s];

    float2 acc[KX];
#pragma unroll
    for (int k = 0; k < KX; k++) acc[k] = make_float2(0.0f, 0.0f);

    for (int e = beg; e < beg + pc; e += 4) {
        uint4 q = *reinterpret_cast<const uint4*>(pairs + e);  // 16B-aligned
        const __half2* r0 = x + (size_t)dec_s(q.x) * H;
        const __half2* r1 = x + (size_t)dec_s(q.y) * H;
        const __half2* r2 = x + (size_t)dec_s(q.z) * H;
        const __half2* r3 = x + (size_t)dec_s(q.w) * H;
        float w0 = dec_w(q.x), w1 = dec_w(q.y), w2 = dec_w(q.z), w3 = dec_w(q.w);
#pragma unroll
        for (int k = 0; k < KX; k++) {
            int m = l + TPN * k;
            if (m < H) {
                float2 v0 = __half22float2(r0[m]);
                float2 v1 = __half22float2(r1[m]);
                float2 v2 = __half22float2(r2[m]);
                float2 v3 = __half22float2(r3[m]);
                acc[k].x += v0.x * w0 + v1.x * w1 + v2.x * w2 + v3.x * w3;
                acc[k].y += v0.y * w0 + v1.y * w1 + v2.y * w2 + v3.y * w3;
            }
        }
    }
    {   // self-loop (weight 1)
        const __half2* rn = x + (size_t)node * H;
#pragma unroll
        for (int k = 0; k < KX; k++) {
            int m = l + TPN * k;
            if (m < H) {
                float2 v = __half22float2(rn[m]);
                acc[k].x += v.x;
                acc[k].y += v.y;
            }
        }
    }
    float dv = dinv[node];
    float p[CPL];
#pragma unroll
    for (int q = 0; q < CPL; q++) p[q] = 0.0f;
#pragma unroll
    for (int m = 0; m < H; m++) {  // broadcast owned pairs to the group
        float ax = __shfl(acc[m / TPN].x, m % TPN, TPN);
        float ay = __shfl(acc[m / TPN].y, m % TPN, TPN);
        const float* w0r = Ws + (2 * m) * P;
        const float* w1r = Ws + (2 * m + 1) * P;
#pragma unroll
        for (int q = 0; q < CPL; q++) {
            int j = l + TPN * q;
            p[q] += ax * w0r[j] + ay * w1r[j];
        }
    }
#pragma unroll
    for (int q = 0; q < CPL; q++) {
        int j = l + TPN * q;
        float a = leaky(dv * p[q] + bs[j]) * dv;
        __half hv = __float2half_rn(a);
        if (j < SPLIT) outA[(size_t)node * SPLIT + j] = hv;
        else outB[(size_t)node * (FOUT - SPLIT) + (j - SPLIT)] = hv;
    }
}

// ---------------- layer-3 gather pass: y = agg(x~half) + self, fp32 [N][6] float2 ----------------
__global__ void k_agg(const int* __restrict__ rowbegS, const int* __restrict__ rowcntS,
                      const int* __restrict__ nodeIdS, const unsigned* __restrict__ pairs,
                      const __half2* __restrict__ xa, float2* __restrict__ y2, int nSlots, int N) {
    constexpr int H = 6;
    int gid = blockIdx.x * blockDim.x + threadIdx.x;
    int s = gid >> 2;
    int l = gid & 3;
    if (s >= nSlots) return;
    int node = nodeIdS[s];
    if (node >= N) return;
    int beg = rowbegS[s], pc = rowcntS[s];
    float2 acc[2];
    acc[0] = make_float2(0.0f, 0.0f);
    acc[1] = make_float2(0.0f, 0.0f);
    for (int e = beg; e < beg + pc; e += 4) {
        uint4 q = *reinterpret_cast<const uint4*>(pairs + e);
        const __half2* r0 = xa + (size_t)dec_s(q.x) * H;
        const __half2* r1 = xa + (size_t)dec_s(q.y) * H;
        const __half2* r2 = xa + (size_t)dec_s(q.z) * H;
        const __half2* r3 = xa + (size_t)dec_s(q.w) * H;
        float w0 = dec_w(q.x), w1 = dec_w(q.y), w2 = dec_w(q.z), w3 = dec_w(q.w);
#pragma unroll
        for (int k = 0; k < 2; k++) {
            int m = l + 4 * k;
            if (m < H) {
                float2 v0 = __half22float2(r0[m]);
                float2 v1 = __half22float2(r1[m]);
                float2 v2 = __half22float2(r2[m]);
                float2 v3 = __half22float2(r3[m]);
                acc[k].x += v0.x * w0 + v1.x * w1 + v2.x * w2 + v3.x * w3;
                acc[k].y += v0.y * w0 + v1.y * w1 + v2.y * w2 + v3.y * w3;
            }
        }
    }
    const __half2* rn = xa + (size_t)node * H;
#pragma unroll
    for (int k = 0; k < 2; k++) {
        int m = l + 4 * k;
        if (m < H) {
            float2 v = __half22float2(rn[m]);
            acc[k].x += v.x;
            acc[k].y += v.y;
            y2[(size_t)node * H + m] = acc[k];
        }
    }
}

// ---------------- layer-3 matmul+pool: stream ya/yb, 24x48, leaky, pool ----------------
// TPN=8: lane l owns output cols j=l+8q (q<6); lanes 0-5 own input slot m=l.
__global__ __launch_bounds__(256) void k_mmpool(
    const float2* __restrict__ ya, const float2* __restrict__ yb,
    const float* __restrict__ dinv, const float* __restrict__ W,
    const float* __restrict__ b, float* __restrict__ g, int N) {
    constexpr int FOUT = 48, P = FOUT + 1, CPL = 6;
    __shared__ float Ws[24 * P];
    __shared__ float bs[FOUT];
    __shared__ float pool[FOUT];
    int t = threadIdx.x;
    for (int i = t; i < 24 * FOUT; i += 256) {
        int r = i / FOUT, c = i - r * FOUT;
        Ws[r * P + c] = W[i];
    }
    for (int i = t; i < FOUT; i += 256) {
        bs[i] = b[i];
        pool[i] = 0.0f;
    }
    __syncthreads();
    int l = t & 7;
    float pacc[CPL];
#pragma unroll
    for (int q = 0; q < CPL; q++) pacc[q] = 0.0f;

    int stride = (int)(gridDim.x * blockDim.x);  // multiple of 8
    for (int idx = blockIdx.x * 256 + t; idx < N * 8; idx += stride) {
        int node = idx >> 3;
        float2 va = (l < 6) ? ya[(size_t)node * 6 + l] : make_float2(0.0f, 0.0f);
        float2 vb = (l < 6) ? yb[(size_t)node * 6 + l] : make_float2(0.0f, 0.0f);
        float dv = dinv[node];
        float p[CPL];
#pragma unroll
        for (int q = 0; q < CPL; q++) p[q] = 0.0f;
#pragma unroll
        for (int m = 0; m < 6; m++) {
            float ax = __shfl(va.x, m, 8);
            float ay = __shfl(va.y, m, 8);
            float bx = __shfl(vb.x, m, 8);
            float by = __shfl(vb.y, m, 8);
            const float* wa0 = Ws + (2 * m) * P;
            const float* wa1 = Ws + (2 * m + 1) * P;
            const float* wb0 = Ws + (12 + 2 * m) * P;
            const float* wb1 = Ws + (12 + 2 * m + 1) * P;
#pragma unroll
            for (int q = 0; q < CPL; q++) {
                int j = l + 8 * q;
                p[q] += ax * wa0[j] + ay * wa1[j] + bx * wb0[j] + by * wb1[j];
            }
        }
#pragma unroll
        for (int q = 0; q < CPL; q++) pacc[q] += leaky(dv * p[q] + bs[l + 8 * q]);
    }
#pragma unroll
    for (int q = 0; q < CPL; q++) atomicAdd(&pool[l + 8 * q], pacc[q]);
    __syncthreads();
    if (t < FOUT) atomicAdd(&g[t], pool[t]);
}

// ---------------- FC head: g[48] -> 32 -> 16 -> 2 ----------------
__global__ void k_head(const float* __restrict__ g,
                       const float* __restrict__ fcW1, const float* __restrict__ fcb1,
                       const float* __restrict__ fcW2, const float* __restrict__ fcb2,
                       const float* __restrict__ fcW3, const float* __restrict__ fcb3,
                       float* __restrict__ out) {
    __shared__ float gs[48], t1[32], t2[16];
    int t = threadIdx.x;
    if (t < 48) gs[t] = g[t];
    __syncthreads();
    if (t < 32) {
        float a = fcb1[t];
#pragma unroll
        for (int k = 0; k < 48; k++) a += gs[k] * fcW1[k * 32 + t];
        t1[t] = leaky(a);
    }
    __syncthreads();
    if (t < 16) {
        float a = fcb2[t];
#pragma unroll
        for (int k = 0; k < 32; k++) a += t1[k] * fcW2[k * 16 + t];
        t2[t] = leaky(a);
    }
    __syncthreads();
    if (t < 2) {
        float a = fcb3[t];
#pragma unroll
        for (int k = 0; k < 16; k++) a += t2[k] * fcW3[k * 2 + t];
        out[t] = a;
    }
}

extern "C" void kernel_launch(void* const* d_in, const int* in_sizes, int n_in,
                              void* d_out, int out_size, void* d_ws, size_t ws_size,
                              hipStream_t stream) {
    const float* xin = (const float*)d_in[0];   // [N,4]
    const float* ew  = (const float*)d_in[1];   // [E]
    const int*   ei  = (const int*)d_in[2];     // [2,E]
    const float* W1  = (const float*)d_in[3];
    const float* b1  = (const float*)d_in[4];
    const float* W2  = (const float*)d_in[5];
    const float* b2  = (const float*)d_in[6];
    const float* W3  = (const float*)d_in[7];
    const float* b3  = (const float*)d_in[8];
    const float* fcW1 = (const float*)d_in[9];
    const float* fcb1 = (const float*)d_in[10];
    const float* fcW2 = (const float*)d_in[11];
    const float* fcb2 = (const float*)d_in[12];
    const float* fcW3 = (const float*)d_in[13];
    const float* fcb3 = (const float*)d_in[14];

    const int N = in_sizes[0] / 4;
    const int E = in_sizes[1];
    const int* src = ei;
    const int* dst = ei + E;
    const int nbins = (N + 255) >> 8;      // 391 for N=100k
    const int nSlots = nbins << 8;         // slot space (>= N)
    const int EPB = cdiv(E, NBLK);

    // workspace layout, 16B-aligned chunks
    char* p_ = (char*)d_ws;
    auto alloc = [&](size_t bytes) { char* r = p_; p_ += (bytes + 15) & ~(size_t)15; return r; };
    unsigned* sortedP = (unsigned*)alloc((size_t)E * 4);
    unsigned* pairs   = (unsigned*)alloc(((size_t)E + (size_t)nbins * BIN_PAD + 16) * 4);
    unsigned char* sortedDlo = (unsigned char*)alloc((size_t)E);
    int*   hist    = (int*)alloc((size_t)BINS_MAX * NBLK * 4);
    int*   binTot  = (int*)alloc((size_t)BINS_MAX * 4);
    int*   binBase = (int*)alloc((size_t)(BINS_MAX + 1) * 4);
    int*   rowbegS = (int*)alloc((size_t)nSlots * 4);
    int*   rowcntS = (int*)alloc((size_t)nSlots * 4);
    int*   nodeIdS = (int*)alloc((size_t)nSlots * 4);
    float* dinv    = (float*)alloc((size_t)N * 4);
    __half2* x0h   = (__half2*)alloc((size_t)N * 2 * 4);   // [N][2]  x~0
    __half*  h1    = (__half*)alloc((size_t)N * 12 * 2);   // [N][12] x~1
    __half*  h2a   = (__half*)alloc((size_t)N * 12 * 2);   // [N][12] x~2 feats 0-11
    __half*  h2b   = (__half*)alloc((size_t)N * 12 * 2);   // [N][12] x~2 feats 12-23
    float2* ya     = (float2*)alloc((size_t)N * 6 * 8);    // [N][6]  l3 agg feats 0-11
    float2* yb     = (float2*)alloc((size_t)N * 6 * 8);    // [N][6]  l3 agg feats 12-23
    float* g       = (float*)alloc(48 * 4);

    // --- sort-based CSR build + node stats (no fabric atomics); k_hist also zeroes g ---
    k_hist<<<NBLK, BT2, 0, stream>>>(dst, hist, g, E, EPB, nbins);
    k_scan_cols<<<nbins, BT, 0, stream>>>(hist, binTot);
    k_scan_bins<<<1, BT, 0, stream>>>(binTot, binBase, nbins);
    k_scatter_bins<<<NBLK, BT2, 0, stream>>>(src, dst, ew, hist, binBase,
                                             sortedP, sortedDlo, E, EPB, nbins);
    k_bin_sort<<<nbins, BT2, 0, stream>>>(sortedP, sortedDlo, binBase, xin, pairs,
                                          rowbegS, rowcntS, nodeIdS, dinv, x0h, N);

    // --- layers 1,2 (slot-indexed lane-split matmul), layer-2 output split into h2a/h2b ---
    k_layer<4, 12, 2, 12><<<cdiv((long long)nSlots * 2, 256), 256, 0, stream>>>(
        rowbegS, rowcntS, nodeIdS, pairs, x0h, dinv, W1, b1, h1, h1, nSlots, N);
    k_layer<12, 24, 4, 12><<<cdiv((long long)nSlots * 4, 256), 256, 0, stream>>>(
        rowbegS, rowcntS, nodeIdS, pairs, (const __half2*)h1, dinv, W2, b2, h2a, h2b, nSlots, N);

    // --- layer 3: two lean gather passes + streaming matmul/pool ---
    k_agg<<<cdiv((long long)nSlots * 4, 256), 256, 0, stream>>>(
        rowbegS, rowcntS, nodeIdS, pairs, (const __half2*)h2a, ya, nSlots, N);
    k_agg<<<cdiv((long long)nSlots * 4, 256), 256, 0, stream>>>(
        rowbegS, rowcntS, nodeIdS, pairs, (const __half2*)h2b, yb, nSlots, N);
    k_mmpool<<<1024, 256, 0, stream>>>(ya, yb, dinv, W3, b3, g, N);

    // --- FC head ---
    k_head<<<1, 64, 0, stream>>>(g, fcW1, fcb1, fcW2, fcb2, fcW3, fcb3, (float*)d_out);
}

// Round 13
// 227.789 us; speedup vs baseline: 4.4062x; 1.1761x over previous
//
#include <hip/hip_runtime.h>
#include <hip/hip_bf16.h>
#include <hip/hip_fp16.h>

static inline int cdiv(long long a, int b) { return (int)((a + b - 1) / b); }

#define LEAK 0.1f
__device__ __forceinline__ float leaky(float v) { return v >= 0.0f ? v : LEAK * v; }

// packed edge: bits[31:15] = src (17b), bits[14:0] = fp16(w) >> 1 ; 0 == zero-pad edge
__device__ __forceinline__ int dec_s(unsigned p) { return (int)(p >> 15); }
__device__ __forceinline__ float dec_w(unsigned p) {
    return __half2float(__ushort_as_half((unsigned short)((p & 0x7FFFu) << 1)));
}
__device__ __forceinline__ unsigned enc_sw(int s, float w) {
    return ((unsigned)s << 15) | ((unsigned)__half_as_ushort(__float2half_rn(w)) >> 1);
}

constexpr int BT = 256;        // threads per block (scan kernels)
constexpr int BT2 = 512;       // threads per block (hist / scatter / bin_sort)
constexpr int NBLK = 512;      // edge-partition blocks (phases A/C)
constexpr int CHUNK = 4096;    // edges staged in LDS per pass (phase C)
constexpr int BINS_MAX = 512;  // >= (N+255)/256 for N=100k (391)
constexpr int BIN_PAD = 1024;  // per-bin slack in pairs[] for row padding

// ---------------- phase A: per-(bin, block) histogram of dst>>8 (also zeroes g) ----------------
__global__ __launch_bounds__(BT2) void k_hist(const int* __restrict__ dst, int* __restrict__ hist,
                                              float* __restrict__ g, int E, int EPB, int nbins) {
    __shared__ int h[BINS_MAX];
    if (blockIdx.x == 0 && threadIdx.x < 48) g[threadIdx.x] = 0.0f;  // pool accumulator init
    for (int i = threadIdx.x; i < nbins; i += BT2) h[i] = 0;
    __syncthreads();
    int base = blockIdx.x * EPB;
    int end = min(base + EPB, E);
    for (int i = base + threadIdx.x; i < end; i += BT2) atomicAdd(&h[dst[i] >> 8], 1);
    __syncthreads();
    for (int i = threadIdx.x; i < nbins; i += BT2) hist[(size_t)i * NBLK + blockIdx.x] = h[i];
}

// ---------------- phase B1: exclusive scan of each bin's row over blocks ----------------
__global__ __launch_bounds__(BT) void k_scan_cols(int* __restrict__ hist, int* __restrict__ binTot) {
    __shared__ int a[NBLK], b_[NBLK];
    int t = threadIdx.x;
    int* H = hist + (size_t)blockIdx.x * NBLK;
    for (int i = t; i < NBLK; i += BT) a[i] = H[i];
    __syncthreads();
    int* cur = a; int* nxt = b_;
    for (int off = 1; off < NBLK; off <<= 1) {
        for (int i = t; i < NBLK; i += BT) nxt[i] = cur[i] + (i >= off ? cur[i - off] : 0);
        __syncthreads();
        int* tm = cur; cur = nxt; nxt = tm;
    }
    for (int i = t; i < NBLK; i += BT) H[i] = (i ? cur[i - 1] : 0);
    if (t == 0) binTot[blockIdx.x] = cur[NBLK - 1];
}

// ---------------- phase B2: exclusive scan over bins ----------------
__global__ __launch_bounds__(BT) void k_scan_bins(const int* __restrict__ binTot,
                                                  int* __restrict__ binBase, int nbins) {
    __shared__ int a[BINS_MAX], b_[BINS_MAX];
    int t = threadIdx.x;
    for (int i = t; i < BINS_MAX; i += BT) a[i] = (i < nbins) ? binTot[i] : 0;
    __syncthreads();
    int* cur = a; int* nxt = b_;
    for (int off = 1; off < BINS_MAX; off <<= 1) {
        for (int i = t; i < BINS_MAX; i += BT) nxt[i] = cur[i] + (i >= off ? cur[i - off] : 0);
        __syncthreads();
        int* tm = cur; cur = nxt; nxt = tm;
    }
    for (int i = t; i < nbins; i += BT) binBase[i] = (i ? cur[i - 1] : 0);
    if (t == 0) binBase[nbins] = cur[nbins - 1];  // == E
}

// ---------------- phase C: LDS-staged scatter of edges into bin order ----------------
__global__ __launch_bounds__(BT2) void k_scatter_bins(
    const int* __restrict__ src, const int* __restrict__ dst, const float* __restrict__ ew,
    const int* __restrict__ colOff, const int* __restrict__ binBase,
    unsigned* __restrict__ sortedP, unsigned char* __restrict__ sortedDlo,
    int E, int EPB, int nbins) {
    constexpr int EPT = CHUNK / BT2;  // 8 edges per thread per chunk
    __shared__ unsigned sP[CHUNK];        // 16 KB
    __shared__ unsigned char sD[CHUNK];   // 4 KB
    __shared__ unsigned short sB[CHUNK];  // 8 KB
    __shared__ int h[BINS_MAX], sc[BINS_MAX], sc2[BINS_MAX];
    __shared__ int blkOff[BINS_MAX], cursor[BINS_MAX];

    int t = threadIdx.x, blk = blockIdx.x;
    if (t < nbins) {
        blkOff[t] = binBase[t] + colOff[(size_t)t * NBLK + blk];
        cursor[t] = 0;
    }
    int base = blk * EPB;
    int bend = min(base + EPB, E);
    for (int cb = base; cb < bend; cb += CHUNK) {
        int cnt = min(CHUNK, bend - cb);
        if (t < BINS_MAX) h[t] = 0;
        __syncthreads();
        int myBin[EPT], myRank[EPT], myD[EPT];
        unsigned myP[EPT];
#pragma unroll
        for (int k = 0; k < EPT; k++) {
            int li = k * BT2 + t;
            if (li < cnt) {
                int i = cb + li;
                int d = dst[i];
                myP[k] = enc_sw(src[i], ew[i]);
                myD[k] = d & 255;
                int b = d >> 8;
                myBin[k] = b;
                myRank[k] = atomicAdd(&h[b], 1);
            } else myBin[k] = -1;
        }
        __syncthreads();
        if (t < BINS_MAX) sc[t] = (t < nbins) ? h[t] : 0;
        __syncthreads();
        int* cur = sc; int* nxt = sc2;
        for (int off = 1; off < BINS_MAX; off <<= 1) {
            if (t < BINS_MAX) nxt[t] = cur[t] + (t >= off ? cur[t - off] : 0);
            __syncthreads();
            int* tm = cur; cur = nxt; nxt = tm;
        }
#pragma unroll
        for (int k = 0; k < EPT; k++) {
            int b = myBin[k];
            if (b >= 0) {
                int pos = (b ? cur[b - 1] : 0) + myRank[k];
                sP[pos] = myP[k];
                sD[pos] = (unsigned char)myD[k];
                sB[pos] = (unsigned short)b;
            }
        }
        __syncthreads();
        for (int i = t; i < cnt; i += BT2) {
            int b = sB[i];
            int excl = (b ? cur[b - 1] : 0);
            int go = blkOff[b] + cursor[b] + (i - excl);
            sortedP[go] = sP[i];
            sortedDlo[go] = sD[i];
        }
        __syncthreads();
        if (t < nbins) cursor[t] += h[t];
        __syncthreads();
    }
}

// ---------------- phase D: per-bin counting sort -> padded CSR + node stats ----------------
// Rows padded to multiple of 4 slots (zero edges), 16B-aligned bases -> uint4 gathers.
__global__ __launch_bounds__(BT2) void k_bin_sort(
    const unsigned* __restrict__ sortedP, const unsigned char* __restrict__ sortedDlo,
    const int* __restrict__ binBase, const float* __restrict__ xin,
    unsigned* __restrict__ pairs, int* __restrict__ rowbeg, int* __restrict__ rowcnt,
    float* __restrict__ dinv, __half2* __restrict__ x0h, int N) {
    __shared__ int cnt[256], a[256], b_[256], cursor[256];
    __shared__ float degs[256];
    int bin = blockIdx.x, t = threadIdx.x;
    int e0 = binBase[bin], e1 = binBase[bin + 1];
    int e0p = ((e0 + 3) & ~3) + bin * BIN_PAD;  // aligned padded base for this bin
    int nodeBase = bin << 8;
    int nn = min(256, N - nodeBase);
    if (t < 256) {
        cnt[t] = 0;
        degs[t] = 0.0f;
    }
    __syncthreads();
    for (int i = e0 + t; i < e1; i += BT2) atomicAdd(&cnt[sortedDlo[i]], 1);
    __syncthreads();
    int realc = 0, pc = 0;
    if (t < 256) {
        realc = cnt[t];
        pc = (realc + 3) & ~3;  // padded count (multiple of 4)
        a[t] = pc;
    }
    __syncthreads();
    int* cur = a; int* nxt = b_;
    for (int off = 1; off < 256; off <<= 1) {
        if (t < 256) nxt[t] = cur[t] + (t >= off ? cur[t - off] : 0);
        __syncthreads();
        int* tm = cur; cur = nxt; nxt = tm;
    }
    int ex = 0;
    if (t < 256) {
        ex = (t ? cur[t - 1] : 0);  // exclusive padded offset
        if (t < nn) {
            rowbeg[nodeBase + t] = e0p + ex;
            rowcnt[nodeBase + t] = pc;
        }
    }
    __syncthreads();
    if (t < 256) {
        cnt[t] = ex;   // repurpose: per-node exclusive padded offset
        cursor[t] = 0;
    }
    __syncthreads();
    for (int i = e0 + t; i < e1; i += BT2) {
        int dl = sortedDlo[i];
        unsigned v = sortedP[i];
        atomicAdd(&degs[dl], dec_w(v));
        int r = atomicAdd(&cursor[dl], 1);
        pairs[e0p + cnt[dl] + r] = v;
    }
    __syncthreads();
    if (t < 256) {
        // zero-fill pad slots of my node
        for (int z = realc; z < pc; z++) pairs[e0p + ex + z] = 0u;
        if (t < nn) {
            int node = nodeBase + t;
            float d = 1.0f + degs[t];
            float di = rsqrtf(d);
            dinv[node] = di;
            float4 xv = *reinterpret_cast<const float4*>(xin + (size_t)node * 4);
            x0h[(size_t)node * 2 + 0] = __floats2half2_rn(xv.x * di, xv.y * di);
            x0h[(size_t)node * 2 + 1] = __floats2half2_rn(xv.z * di, xv.w * di);
        }
    }
}

// ---------------- fused layer (layers 1,2): lane-split output columns ----------------
template <int FIN, int FOUT, int TPN, int SPLIT>
__global__ void k_layer(const int* __restrict__ rowbeg, const int* __restrict__ rowcnt,
                        const unsigned* __restrict__ pairs,
                        const __half2* __restrict__ x, const float* __restrict__ dinv,
                        const float* __restrict__ W, const float* __restrict__ b,
                        __half* __restrict__ outA, __half* __restrict__ outB, int N) {
    constexpr int H = FIN / 2;
    constexpr int P = FOUT + 1;
    constexpr int KX = (H + TPN - 1) / TPN;
    constexpr int CPL = FOUT / TPN;  // columns per lane
    __shared__ float Ws[FIN * P];
    __shared__ float bs[FOUT];
    for (int t = threadIdx.x; t < FIN * FOUT; t += blockDim.x) {
        int r = t / FOUT, c = t - r * FOUT;
        Ws[r * P + c] = W[t];
    }
    for (int t = threadIdx.x; t < FOUT; t += blockDim.x) bs[t] = b[t];
    __syncthreads();
    int gid = blockIdx.x * blockDim.x + threadIdx.x;
    int node = gid / TPN;
    int l = gid & (TPN - 1);
    if (node >= N) return;
    int beg = rowbeg[node], pc = rowcnt[node];

    float2 acc[KX];
#pragma unroll
    for (int k = 0; k < KX; k++) acc[k] = make_float2(0.0f, 0.0f);

    for (int e = beg; e < beg + pc; e += 4) {
        uint4 q = *reinterpret_cast<const uint4*>(pairs + e);  // 16B-aligned
        const __half2* r0 = x + (size_t)dec_s(q.x) * H;
        const __half2* r1 = x + (size_t)dec_s(q.y) * H;
        const __half2* r2 = x + (size_t)dec_s(q.z) * H;
        const __half2* r3 = x + (size_t)dec_s(q.w) * H;
        float w0 = dec_w(q.x), w1 = dec_w(q.y), w2 = dec_w(q.z), w3 = dec_w(q.w);
#pragma unroll
        for (int k = 0; k < KX; k++) {
            int m = l + TPN * k;
            if (m < H) {
                float2 v0 = __half22float2(r0[m]);
                float2 v1 = __half22float2(r1[m]);
                float2 v2 = __half22float2(r2[m]);
                float2 v3 = __half22float2(r3[m]);
                acc[k].x += v0.x * w0 + v1.x * w1 + v2.x * w2 + v3.x * w3;
                acc[k].y += v0.y * w0 + v1.y * w1 + v2.y * w2 + v3.y * w3;
            }
        }
    }
    {   // self-loop (weight 1)
        const __half2* rn = x + (size_t)node * H;
#pragma unroll
        for (int k = 0; k < KX; k++) {
            int m = l + TPN * k;
            if (m < H) {
                float2 v = __half22float2(rn[m]);
                acc[k].x += v.x;
                acc[k].y += v.y;
            }
        }
    }
    float dv = dinv[node];
    float p[CPL];
#pragma unroll
    for (int q = 0; q < CPL; q++) p[q] = 0.0f;
#pragma unroll
    for (int m = 0; m < H; m++) {  // broadcast owned pairs to the group
        float ax = __shfl(acc[m / TPN].x, m % TPN, TPN);
        float ay = __shfl(acc[m / TPN].y, m % TPN, TPN);
        const float* w0r = Ws + (2 * m) * P;
        const float* w1r = Ws + (2 * m + 1) * P;
#pragma unroll
        for (int q = 0; q < CPL; q++) {
            int j = l + TPN * q;
            p[q] += ax * w0r[j] + ay * w1r[j];
        }
    }
#pragma unroll
    for (int q = 0; q < CPL; q++) {
        int j = l + TPN * q;
        float a = leaky(dv * p[q] + bs[j]) * dv;
        __half hv = __float2half_rn(a);
        if (j < SPLIT) outA[(size_t)node * SPLIT + j] = hv;
        else outB[(size_t)node * (FOUT - SPLIT) + (j - SPLIT)] = hv;
    }
}

// ---------------- layer-3 pass A: y = agg(h2a) + self, fp32 [N][6] float2 ----------------
__global__ void k_agg(const int* __restrict__ rowbeg, const int* __restrict__ rowcnt,
                      const unsigned* __restrict__ pairs,
                      const __half2* __restrict__ xa, float2* __restrict__ y2, int N) {
    constexpr int H = 6;
    int gid = blockIdx.x * blockDim.x + threadIdx.x;
    int node = gid >> 2;
    int l = gid & 3;
    if (node >= N) return;
    int beg = rowbeg[node], pc = rowcnt[node];
    float2 acc[2];
    acc[0] = make_float2(0.0f, 0.0f);
    acc[1] = make_float2(0.0f, 0.0f);
    for (int e = beg; e < beg + pc; e += 4) {
        uint4 q = *reinterpret_cast<const uint4*>(pairs + e);
        const __half2* r0 = xa + (size_t)dec_s(q.x) * H;
        const __half2* r1 = xa + (size_t)dec_s(q.y) * H;
        const __half2* r2 = xa + (size_t)dec_s(q.z) * H;
        const __half2* r3 = xa + (size_t)dec_s(q.w) * H;
        float w0 = dec_w(q.x), w1 = dec_w(q.y), w2 = dec_w(q.z), w3 = dec_w(q.w);
#pragma unroll
        for (int k = 0; k < 2; k++) {
            int m = l + 4 * k;
            if (m < H) {
                float2 v0 = __half22float2(r0[m]);
                float2 v1 = __half22float2(r1[m]);
                float2 v2 = __half22float2(r2[m]);
                float2 v3 = __half22float2(r3[m]);
                acc[k].x += v0.x * w0 + v1.x * w1 + v2.x * w2 + v3.x * w3;
                acc[k].y += v0.y * w0 + v1.y * w1 + v2.y * w2 + v3.y * w3;
            }
        }
    }
    const __half2* rn = xa + (size_t)node * H;
#pragma unroll
    for (int k = 0; k < 2; k++) {
        int m = l + 4 * k;
        if (m < H) {
            float2 v = __half22float2(rn[m]);
            acc[k].x += v.x;
            acc[k].y += v.y;
            y2[(size_t)node * H + m] = acc[k];
        }
    }
}

// ---------------- layer-3 pass B (fused): gather h2b + ya -> 24x48 matmul + leaky + pool ----------------
// TPN=8 grid-stride. Lane l<6 gathers h2b half2 slot m=l (acc) and loads ya slot l.
// Shfl-broadcast over the 8-lane group; lane l owns output cols j=l+8q (q<6).
__global__ __launch_bounds__(256) void k_aggmm(
    const int* __restrict__ rowbeg, const int* __restrict__ rowcnt,
    const unsigned* __restrict__ pairs, const __half2* __restrict__ xb,
    const float2* __restrict__ ya, const float* __restrict__ dinv,
    const float* __restrict__ W, const float* __restrict__ b,
    float* __restrict__ g, int N) {
    constexpr int H = 6, FOUT = 48, P = FOUT + 1, CPL = 6;
    __shared__ float Ws[24 * P];
    __shared__ float bs[FOUT];
    __shared__ float pool[FOUT];
    int t = threadIdx.x;
    for (int i = t; i < 24 * FOUT; i += 256) Ws[(i / FOUT) * P + (i % FOUT)] = W[i];
    for (int i = t; i < FOUT; i += 256) {
        bs[i] = b[i];
        pool[i] = 0.0f;
    }
    __syncthreads();
    int l = t & 7;
    float pacc[CPL];
#pragma unroll
    for (int q = 0; q < CPL; q++) pacc[q] = 0.0f;

    int stride = (int)(gridDim.x * blockDim.x);  // multiple of 8
    for (int idx = blockIdx.x * 256 + t; idx < N * 8; idx += stride) {
        int node = idx >> 3;
        float2 acc = make_float2(0.0f, 0.0f);
        float2 va = make_float2(0.0f, 0.0f);
        if (l < 6) {
            int beg = rowbeg[node], pc = rowcnt[node];
            for (int e = beg; e < beg + pc; e += 4) {
                uint4 q = *reinterpret_cast<const uint4*>(pairs + e);
                float2 v0 = __half22float2(xb[(size_t)dec_s(q.x) * H + l]);
                float2 v1 = __half22float2(xb[(size_t)dec_s(q.y) * H + l]);
                float2 v2 = __half22float2(xb[(size_t)dec_s(q.z) * H + l]);
                float2 v3 = __half22float2(xb[(size_t)dec_s(q.w) * H + l]);
                float w0 = dec_w(q.x), w1 = dec_w(q.y), w2 = dec_w(q.z), w3 = dec_w(q.w);
                acc.x += v0.x * w0 + v1.x * w1 + v2.x * w2 + v3.x * w3;
                acc.y += v0.y * w0 + v1.y * w1 + v2.y * w2 + v3.y * w3;
            }
            float2 s = __half22float2(xb[(size_t)node * H + l]);  // self-loop
            acc.x += s.x;
            acc.y += s.y;
            va = ya[(size_t)node * H + l];
        }
        float dv = dinv[node];
        float p[CPL];
#pragma unroll
        for (int q = 0; q < CPL; q++) p[q] = 0.0f;
#pragma unroll
        for (int m = 0; m < 6; m++) {
            float ax = __shfl(va.x, m, 8);
            float ay = __shfl(va.y, m, 8);
            float bx = __shfl(acc.x, m, 8);
            float by = __shfl(acc.y, m, 8);
            const float* wa0 = Ws + (2 * m) * P;
            const float* wa1 = Ws + (2 * m + 1) * P;
            const float* wb0 = Ws + (12 + 2 * m) * P;
            const float* wb1 = Ws + (12 + 2 * m + 1) * P;
#pragma unroll
            for (int q = 0; q < CPL; q++) {
                int j = l + 8 * q;
                p[q] += ax * wa0[j] + ay * wa1[j] + bx * wb0[j] + by * wb1[j];
            }
        }
#pragma unroll
        for (int q = 0; q < CPL; q++) pacc[q] += leaky(dv * p[q] + bs[l + 8 * q]);
    }
#pragma unroll
    for (int q = 0; q < CPL; q++) atomicAdd(&pool[l + 8 * q], pacc[q]);
    __syncthreads();
    if (t < FOUT) atomicAdd(&g[t], pool[t]);
}

// ---------------- FC head: g[48] -> 32 -> 16 -> 2 ----------------
__global__ void k_head(const float* __restrict__ g,
                       const float* __restrict__ fcW1, const float* __restrict__ fcb1,
                       const float* __restrict__ fcW2, const float* __restrict__ fcb2,
                       const float* __restrict__ fcW3, const float* __restrict__ fcb3,
                       float* __restrict__ out) {
    __shared__ float gs[48], t1[32], t2[16];
    int t = threadIdx.x;
    if (t < 48) gs[t] = g[t];
    __syncthreads();
    if (t < 32) {
        float a = fcb1[t];
#pragma unroll
        for (int k = 0; k < 48; k++) a += gs[k] * fcW1[k * 32 + t];
        t1[t] = leaky(a);
    }
    __syncthreads();
    if (t < 16) {
        float a = fcb2[t];
#pragma unroll
        for (int k = 0; k < 32; k++) a += t1[k] * fcW2[k * 16 + t];
        t2[t] = leaky(a);
    }
    __syncthreads();
    if (t < 2) {
        float a = fcb3[t];
#pragma unroll
        for (int k = 0; k < 16; k++) a += t2[k] * fcW3[k * 2 + t];
        out[t] = a;
    }
}

extern "C" void kernel_launch(void* const* d_in, const int* in_sizes, int n_in,
                              void* d_out, int out_size, void* d_ws, size_t ws_size,
                              hipStream_t stream) {
    const float* xin = (const float*)d_in[0];   // [N,4]
    const float* ew  = (const float*)d_in[1];   // [E]
    const int*   ei  = (const int*)d_in[2];     // [2,E]
    const float* W1  = (const float*)d_in[3];
    const float* b1  = (const float*)d_in[4];
    const float* W2  = (const float*)d_in[5];
    const float* b2  = (const float*)d_in[6];
    const float* W3  = (const float*)d_in[7];
    const float* b3  = (const float*)d_in[8];
    const float* fcW1 = (const float*)d_in[9];
    const float* fcb1 = (const float*)d_in[10];
    const float* fcW2 = (const float*)d_in[11];
    const float* fcb2 = (const float*)d_in[12];
    const float* fcW3 = (const float*)d_in[13];
    const float* fcb3 = (const float*)d_in[14];

    const int N = in_sizes[0] / 4;
    const int E = in_sizes[1];
    const int* src = ei;
    const int* dst = ei + E;
    const int nbins = (N + 255) >> 8;      // 391 for N=100k
    const int EPB = cdiv(E, NBLK);

    // workspace layout, 16B-aligned chunks
    char* p_ = (char*)d_ws;
    auto alloc = [&](size_t bytes) { char* r = p_; p_ += (bytes + 15) & ~(size_t)15; return r; };
    unsigned* sortedP = (unsigned*)alloc((size_t)E * 4);
    unsigned* pairs   = (unsigned*)alloc(((size_t)E + (size_t)nbins * BIN_PAD + 16) * 4);
    unsigned char* sortedDlo = (unsigned char*)alloc((size_t)E);
    int*   hist    = (int*)alloc((size_t)BINS_MAX * NBLK * 4);
    int*   binTot  = (int*)alloc((size_t)BINS_MAX * 4);
    int*   binBase = (int*)alloc((size_t)(BINS_MAX + 1) * 4);
    int*   rowbeg  = (int*)alloc((size_t)N * 4);
    int*   rowcnt  = (int*)alloc((size_t)N * 4);
    float* dinv    = (float*)alloc((size_t)N * 4);
    __half2* x0h   = (__half2*)alloc((size_t)N * 2 * 4);   // [N][2]  x~0
    __half*  h1    = (__half*)alloc((size_t)N * 12 * 2);   // [N][12] x~1
    __half*  h2a   = (__half*)alloc((size_t)N * 12 * 2);   // [N][12] x~2 feats 0-11
    __half*  h2b   = (__half*)alloc((size_t)N * 12 * 2);   // [N][12] x~2 feats 12-23
    float2* ya     = (float2*)alloc((size_t)N * 6 * 8);    // [N][6]  l3 agg feats 0-11
    float* g       = (float*)alloc(48 * 4);

    // --- sort-based CSR build + node stats (no fabric atomics); k_hist also zeroes g ---
    k_hist<<<NBLK, BT2, 0, stream>>>(dst, hist, g, E, EPB, nbins);
    k_scan_cols<<<nbins, BT, 0, stream>>>(hist, binTot);
    k_scan_bins<<<1, BT, 0, stream>>>(binTot, binBase, nbins);
    k_scatter_bins<<<NBLK, BT2, 0, stream>>>(src, dst, ew, hist, binBase,
                                             sortedP, sortedDlo, E, EPB, nbins);
    k_bin_sort<<<nbins, BT2, 0, stream>>>(sortedP, sortedDlo, binBase, xin,
                                          pairs, rowbeg, rowcnt, dinv, x0h, N);

    // --- layers 1,2 (lane-split matmul), layer-2 output split into h2a/h2b ---
    k_layer<4, 12, 2, 12><<<cdiv((long long)N * 2, 256), 256, 0, stream>>>(
        rowbeg, rowcnt, pairs, x0h, dinv, W1, b1, h1, h1, N);
    k_layer<12, 24, 4, 12><<<cdiv((long long)N * 4, 256), 256, 0, stream>>>(
        rowbeg, rowcnt, pairs, (const __half2*)h1, dinv, W2, b2, h2a, h2b, N);

    // --- layer 3: lean gather pass (h2a) + fused gather/matmul/pool pass (h2b) ---
    k_agg<<<cdiv((long long)N * 4, 256), 256, 0, stream>>>(
        rowbeg, rowcnt, pairs, (const __half2*)h2a, ya, N);
    k_aggmm<<<1024, 256, 0, stream>>>(
        rowbeg, rowcnt, pairs, (const __half2*)h2b, ya, dinv, W3, b3, g, N);

    // --- FC head ---
    k_head<<<1, 64, 0, stream>>>(g, fcW1, fcb1, fcW2, fcb2, fcW3, fcb3, (float*)d_out);
}